// Round 6
// baseline (214.035 us; speedup 1.0000x reference)
//
#include <hip/hip_runtime.h>

#define N_NODES 100000
#define N_EDGES 1250000
#define D 64
#define NPB 256                  // nodes per coarse bucket (dst >> 8)
#define NB  391                  // ceil(N_NODES / NPB)
#define NPAD2 (NB * NPB)         // 100096
#define EPT 16                   // edges per thread in hist/place
#define EPB (256 * EPT)          // 4096 edges per block
#define NBLK ((N_EDGES + EPB - 1) / EPB)   // 306

// ---------------- coarse histogram: LDS first, 391 global adds per block ----------------
__global__ __launch_bounds__(256) void hist_kernel(const int* __restrict__ dst,
                                                   int* __restrict__ bhist) {
    __shared__ int h[NB];
    int t = threadIdx.x;
    for (int i = t; i < NB; i += 256) h[i] = 0;
    __syncthreads();
    int base = blockIdx.x * EPB;
    #pragma unroll
    for (int i = 0; i < EPT; ++i) {
        int e = base + t + i * 256;
        if (e < N_EDGES) atomicAdd(&h[dst[e] >> 8], 1);
    }
    __syncthreads();
    for (int i = t; i < NB; i += 256)
        if (h[i]) atomicAdd(&bhist[i], h[i]);
}

// ---------------- scan 391 bucket counts -> boffs + gcursor ----------------
__global__ __launch_bounds__(512) void bucket_scan_kernel(const int* __restrict__ bhist,
                                                          int* __restrict__ boffs,
                                                          int* __restrict__ gcursor) {
    __shared__ int lds[512];
    int t = threadIdx.x;
    int v = (t < NB) ? bhist[t] : 0;
    int inc = v;
    lds[t] = inc;
    __syncthreads();
    for (int off = 1; off < 512; off <<= 1) {
        int y = (t >= off) ? lds[t - off] : 0;
        __syncthreads();
        inc += y;
        lds[t] = inc;
        __syncthreads();
    }
    int exc = inc - v;
    if (t < NB) { boffs[t] = exc; gcursor[t] = exc; }
    if (t == NB - 1) boffs[NB] = exc + v;
}

// ---------------- place: block-level range reservation + LDS cursors ----------------
__global__ __launch_bounds__(256) void place_kernel(const int* __restrict__ src,
                                                    const int* __restrict__ dst,
                                                    int* __restrict__ gcursor,
                                                    unsigned int* __restrict__ packed) {
    __shared__ int h[NB];
    __shared__ int cur[NB];
    int t = threadIdx.x;
    for (int i = t; i < NB; i += 256) h[i] = 0;
    __syncthreads();
    int base = blockIdx.x * EPB;
    int d[EPT];
    #pragma unroll
    for (int i = 0; i < EPT; ++i) {
        int e = base + t + i * 256;
        d[i] = (e < N_EDGES) ? dst[e] : -1;
        if (d[i] >= 0) atomicAdd(&h[d[i] >> 8], 1);
    }
    __syncthreads();
    for (int i = t; i < NB; i += 256)
        cur[i] = h[i] ? atomicAdd(&gcursor[i], h[i]) : 0;   // reserve block's range
    __syncthreads();
    #pragma unroll
    for (int i = 0; i < EPT; ++i) {
        if (d[i] >= 0) {
            int e = base + t + i * 256;
            int pos = atomicAdd(&cur[d[i] >> 8], 1);
            packed[pos] = ((unsigned)src[e] << 8) | (unsigned)(d[i] & 255);
        }
    }
}

// ---------------- refine: per-bucket exact CSR (offs, ssorted) + norm ----------------
__global__ __launch_bounds__(256) void refine_kernel(const unsigned int* __restrict__ packed,
                                                     const int* __restrict__ boffs,
                                                     int* __restrict__ ssorted,
                                                     int* __restrict__ offs,
                                                     float* __restrict__ norm) {
    __shared__ int h[NPB];
    __shared__ int sc[NPB];
    __shared__ int cur[NPB];
    int b = blockIdx.x, t = threadIdx.x;
    int beg = boffs[b], end = boffs[b + 1];
    h[t] = 0;
    __syncthreads();
    for (int j = beg + t; j < end; j += 256)
        atomicAdd(&h[packed[j] & 255], 1);
    __syncthreads();
    int v = h[t], inc = v;
    sc[t] = inc;
    __syncthreads();
    for (int off = 1; off < 256; off <<= 1) {
        int y = (t >= off) ? sc[t - off] : 0;
        __syncthreads();
        inc += y;
        sc[t] = inc;
        __syncthreads();
    }
    int exc = inc - v;
    cur[t] = beg + exc;
    int n = b * NPB + t;
    offs[n] = beg + exc;                  // offs[100000] lands correctly (= N_EDGES)
    if (n < N_NODES) norm[n] = rsqrtf((float)(v < 1 ? 1 : v));
    __syncthreads();
    for (int j = beg + t; j < end; j += 256) {
        unsigned p = packed[j];
        int pos = atomicAdd(&cur[p & 255], 1);
        ssorted[pos] = (int)(p >> 8);
    }
}

// ---------------- prep: featn[n][k] = bf16(feat[n][k] * norm[n]) ----------------
__global__ __launch_bounds__(256) void prep_kernel(const float* __restrict__ feat,
                                                   const float* __restrict__ norm,
                                                   unsigned short* __restrict__ featn) {
    int g = blockIdx.x * 256 + threadIdx.x;       // < 1,600,000
    int n = g >> 4;                               // 16 threads per row
    float nn = norm[n];
    float4 f = *(const float4*)&feat[(size_t)g * 4];
    auto cvt = [](float x) -> unsigned {          // bf16 RNE, keep in low 16
        unsigned u = __float_as_uint(x);
        return (u + 0x7fff + ((u >> 16) & 1)) >> 16;
    };
    unsigned r0 = cvt(f.x * nn) | (cvt(f.y * nn) << 16);
    unsigned r1 = cvt(f.z * nn) | (cvt(f.w * nn) << 16);
    *(uint2*)&featn[(size_t)g * 4] = make_uint2(r0, r1);
}

// ---------------- gather (bf16): one wave per node, 4 edges per load instr ----------------
// lane = (q = edge slot 0..3) * 16 + (m = column quarter 0..15); 8 B/lane covers the 128 B row
__global__ __launch_bounds__(256) void gather_bf16_kernel(const unsigned short* __restrict__ featn,
                                                          const int* __restrict__ ssorted,
                                                          const int* __restrict__ offs,
                                                          const float* __restrict__ norm,
                                                          float* __restrict__ out) {
    int n = blockIdx.x * 4 + (threadIdx.x >> 6);
    int lane = threadIdx.x & 63;
    if (n >= N_NODES) return;
    int beg = offs[n], end = offs[n + 1];
    int q = lane >> 4, m = lane & 15;
    float4 acc = make_float4(0.f, 0.f, 0.f, 0.f);

    #define ACC_EDGE(J) do {                                              \
        int s = ssorted[(J)];                                             \
        uint2 r = *(const uint2*)&featn[(size_t)s * D + m * 4];           \
        acc.x += __uint_as_float(r.x << 16);                              \
        acc.y += __uint_as_float(r.x & 0xffff0000u);                      \
        acc.z += __uint_as_float(r.y << 16);                              \
        acc.w += __uint_as_float(r.y & 0xffff0000u);                      \
    } while (0)

    int j = beg;
    for (; j + 16 <= end; j += 16) {
        #pragma unroll
        for (int g = 0; g < 4; ++g) ACC_EDGE(j + 4 * g + q);
    }
    for (; j + 4 <= end; j += 4) ACC_EDGE(j + q);
    if (j + q < end) ACC_EDGE(j + q);
    #undef ACC_EDGE

    #pragma unroll
    for (int mask = 16; mask <= 32; mask <<= 1) {
        acc.x += __shfl_xor(acc.x, mask);
        acc.y += __shfl_xor(acc.y, mask);
        acc.z += __shfl_xor(acc.z, mask);
        acc.w += __shfl_xor(acc.w, mask);
    }
    if (q == 0) {
        float nn = norm[n];
        *(float4*)&out[(size_t)n * D + m * 4] =
            make_float4(acc.x * nn, acc.y * nn, acc.z * nn, acc.w * nn);
    }
}

// ---------------- gather (fp32 fallback, proven R4 path) ----------------
__global__ __launch_bounds__(256) void gather_f32_kernel(const float* __restrict__ feat,
                                                         const int* __restrict__ ssorted,
                                                         const int* __restrict__ offs,
                                                         const float* __restrict__ norm,
                                                         float* __restrict__ out) {
    int n = blockIdx.x * 4 + (threadIdx.x >> 6);
    int lane = threadIdx.x & 63;
    if (n >= N_NODES) return;
    int beg = offs[n], end = offs[n + 1];
    int q = lane >> 4, m = lane & 15;
    float4 acc = make_float4(0.f, 0.f, 0.f, 0.f);
    int j = beg;
    for (; j + 16 <= end; j += 16) {
        #pragma unroll
        for (int g = 0; g < 4; ++g) {
            int s = ssorted[j + 4 * g + q];
            float4 f = *(const float4*)&feat[(size_t)s * D + m * 4];
            float ns = norm[s];
            acc.x += f.x * ns; acc.y += f.y * ns; acc.z += f.z * ns; acc.w += f.w * ns;
        }
    }
    for (; j + 4 <= end; j += 4) {
        int s = ssorted[j + q];
        float4 f = *(const float4*)&feat[(size_t)s * D + m * 4];
        float ns = norm[s];
        acc.x += f.x * ns; acc.y += f.y * ns; acc.z += f.z * ns; acc.w += f.w * ns;
    }
    if (j + q < end) {
        int s = ssorted[j + q];
        float4 f = *(const float4*)&feat[(size_t)s * D + m * 4];
        float ns = norm[s];
        acc.x += f.x * ns; acc.y += f.y * ns; acc.z += f.z * ns; acc.w += f.w * ns;
    }
    #pragma unroll
    for (int mask = 16; mask <= 32; mask <<= 1) {
        acc.x += __shfl_xor(acc.x, mask);
        acc.y += __shfl_xor(acc.y, mask);
        acc.z += __shfl_xor(acc.z, mask);
        acc.w += __shfl_xor(acc.w, mask);
    }
    if (q == 0) {
        float nn = norm[n];
        *(float4*)&out[(size_t)n * D + m * 4] =
            make_float4(acc.x * nn, acc.y * nn, acc.z * nn, acc.w * nn);
    }
}

// ---------------- GEMM: out = h @ W^T + bias, in-place on d_out ----------------
#define GPAD 68
__global__ __launch_bounds__(256) void gemm64_kernel(const float* __restrict__ weight,
                                                     const float* __restrict__ bias,
                                                     float* __restrict__ io) {
    __shared__ float Ht[D * GPAD];   // Ht[k][n]
    __shared__ float Wt[D * GPAD];   // Wt[k][d]
    int tid = threadIdx.x;
    int n0 = blockIdx.x * 64;
    int c = tid & 63;
    int r4 = tid >> 6;

    for (int dd = r4; dd < D; dd += 4)
        Wt[c * GPAD + dd] = weight[dd * D + c];
    for (int nl = r4; nl < 64; nl += 4) {
        int n = n0 + nl;
        Ht[c * GPAD + nl] = (n < N_NODES) ? io[(size_t)n * D + c] : 0.f;
    }
    __syncthreads();

    int tx = tid & 15, ty = tid >> 4;
    float acc[4][4] = {};
    #pragma unroll 8
    for (int k = 0; k < D; ++k) {
        float4 a = *(const float4*)&Ht[k * GPAD + ty * 4];
        float4 b = *(const float4*)&Wt[k * GPAD + tx * 4];
        acc[0][0] += a.x * b.x; acc[0][1] += a.x * b.y; acc[0][2] += a.x * b.z; acc[0][3] += a.x * b.w;
        acc[1][0] += a.y * b.x; acc[1][1] += a.y * b.y; acc[1][2] += a.y * b.z; acc[1][3] += a.y * b.w;
        acc[2][0] += a.z * b.x; acc[2][1] += a.z * b.y; acc[2][2] += a.z * b.z; acc[2][3] += a.z * b.w;
        acc[3][0] += a.w * b.x; acc[3][1] += a.w * b.y; acc[3][2] += a.w * b.z; acc[3][3] += a.w * b.w;
    }

    float4 bv = *(const float4*)&bias[tx * 4];
    #pragma unroll
    for (int i = 0; i < 4; ++i) {
        int n = n0 + ty * 4 + i;
        if (n < N_NODES) {
            *(float4*)&io[(size_t)n * D + tx * 4] =
                make_float4(acc[i][0] + bv.x, acc[i][1] + bv.y,
                            acc[i][2] + bv.z, acc[i][3] + bv.w);
        }
    }
}

extern "C" void kernel_launch(void* const* d_in, const int* in_sizes, int n_in,
                              void* d_out, int out_size, void* d_ws, size_t ws_size,
                              hipStream_t stream) {
    const float* feat   = (const float*)d_in[0];
    const int*   src    = (const int*)d_in[1];
    const int*   dst    = (const int*)d_in[2];
    const float* weight = (const float*)d_in[3];
    const float* bias   = (const float*)d_in[4];
    float* out = (float*)d_out;

    // workspace layout (bytes):
    //   [0)            bhist[NB], boffs[NB+1], gcursor[NB]        ~4.7 KB
    //   [...]          offs[NPAD2], norm[NPAD2]                    800 KB
    //   [805,464)      ssorted[N_EDGES]                            5 MB   -> ends 5,805,464
    //   [5,805,464)    featn region, 12.8 MB; packed overlays its first 5 MB
    //                  (packed dead after refine; prep runs after refine)
    // high water: 18,605,464 B
    int* w = (int*)d_ws;
    int*      bhist   = w;                           // [NB]
    int*      boffs   = bhist + NB;                  // [NB+1]
    int*      gcursor = boffs + NB + 1;              // [NB]
    int*      offs    = gcursor + NB;                // [NPAD2]
    float*    norm    = (float*)(offs + NPAD2);      // [NPAD2]
    int*      ssorted = (int*)(norm + NPAD2);        // [N_EDGES]
    unsigned* packed  = (unsigned*)(ssorted + N_EDGES);      // [N_EDGES]
    unsigned short* featn = (unsigned short*)packed;         // [N_NODES*D] bf16

    const size_t REQUIRED = (size_t)((3 * NB + 1) + 2 * NPAD2 + N_EDGES) * 4
                          + (size_t)N_NODES * D * 2;   // 18,605,464
    bool use_bf16 = ws_size >= REQUIRED;

    hipMemsetAsync(bhist, 0, NB * sizeof(int), stream);

    hist_kernel       <<<NBLK, 256, 0, stream>>>(dst, bhist);
    bucket_scan_kernel<<<1, 512, 0, stream>>>(bhist, boffs, gcursor);
    place_kernel      <<<NBLK, 256, 0, stream>>>(src, dst, gcursor, packed);
    refine_kernel     <<<NB, 256, 0, stream>>>(packed, boffs, ssorted, offs, norm);
    if (use_bf16) {
        prep_kernel       <<<(N_NODES * D / 4) / 256, 256, 0, stream>>>(feat, norm, featn);
        gather_bf16_kernel<<<(N_NODES + 3) / 4, 256, 0, stream>>>(featn, ssorted, offs, norm, out);
    } else {
        gather_f32_kernel <<<(N_NODES + 3) / 4, 256, 0, stream>>>(feat, ssorted, offs, norm, out);
    }
    gemm64_kernel     <<<(N_NODES + 63) / 64, 256, 0, stream>>>(weight, bias, out);
}

// Round 7
// 203.959 us; speedup vs baseline: 1.0494x; 1.0494x over previous
//
#include <hip/hip_runtime.h>

#define N_NODES 100000
#define N_EDGES 1250000
#define D 64
#define NPB 256                  // nodes per coarse bucket (dst >> 8)
#define NB  391                  // ceil(N_NODES / NPB)
#define NPAD2 (NB * NPB)         // 100096
#define EPT 16                   // edges per thread in hist/place
#define EPB (256 * EPT)          // 4096 edges per block
#define NBLK ((N_EDGES + EPB - 1) / EPB)   // 306
#define CAPPAD 1792              // per-bucket extra capacity for pad-to-8 (256*7)
#define SSP_CAP (N_EDGES + NB * CAPPAD)    // 1,950,672
#define DUMMY N_NODES            // featn[DUMMY] is a zero row

// ---------------- coarse histogram: LDS first, 391 global adds per block ----------------
__global__ __launch_bounds__(256) void hist_kernel(const int* __restrict__ dst,
                                                   int* __restrict__ bhist) {
    __shared__ int h[NB];
    int t = threadIdx.x;
    for (int i = t; i < NB; i += 256) h[i] = 0;
    __syncthreads();
    int base = blockIdx.x * EPB;
    #pragma unroll
    for (int i = 0; i < EPT; ++i) {
        int e = base + t + i * 256;
        if (e < N_EDGES) atomicAdd(&h[dst[e] >> 8], 1);
    }
    __syncthreads();
    for (int i = t; i < NB; i += 256)
        if (h[i]) atomicAdd(&bhist[i], h[i]);
}

// ---------------- scan 391 bucket counts -> boffs + gcursor ----------------
__global__ __launch_bounds__(512) void bucket_scan_kernel(const int* __restrict__ bhist,
                                                          int* __restrict__ boffs,
                                                          int* __restrict__ gcursor) {
    __shared__ int lds[512];
    int t = threadIdx.x;
    int v = (t < NB) ? bhist[t] : 0;
    int inc = v;
    lds[t] = inc;
    __syncthreads();
    for (int off = 1; off < 512; off <<= 1) {
        int y = (t >= off) ? lds[t - off] : 0;
        __syncthreads();
        inc += y;
        lds[t] = inc;
        __syncthreads();
    }
    int exc = inc - v;
    if (t < NB) { boffs[t] = exc; gcursor[t] = exc; }
    if (t == NB - 1) boffs[NB] = exc + v;
}

// ---------------- place: local counting sort, ascending-address emission ----------------
__global__ __launch_bounds__(256) void place_kernel(const int* __restrict__ src,
                                                    const int* __restrict__ dst,
                                                    int* __restrict__ gcursor,
                                                    unsigned int* __restrict__ packed) {
    __shared__ int h[512];                 // bin counts (padded to 512)
    __shared__ int ps[256];                // pair-scan workspace
    __shared__ int lstart[NB];             // local exclusive start per bin
    __shared__ int gbase[NB];              // reserved global base per bin
    __shared__ int lcur[NB];               // local scatter cursor
    __shared__ unsigned sortedv[EPB];      // 16 KB locally-sorted packed values
    __shared__ unsigned short binof[EPB];  // 8 KB bin of each sorted slot
    int t = threadIdx.x;
    h[t] = 0; h[t + 256] = 0;
    __syncthreads();

    int base = blockIdx.x * EPB;
    int d[EPT], s[EPT];
    #pragma unroll
    for (int i = 0; i < EPT; ++i) {
        int e = base + t + i * 256;
        if (e < N_EDGES) {
            d[i] = dst[e]; s[i] = src[e];
            atomicAdd(&h[d[i] >> 8], 1);
        } else d[i] = -1;
    }
    __syncthreads();

    // scan 512 bins with 256 threads: pair-combine then Hillis-Steele on pairs
    int a0 = h[2 * t], a1 = h[2 * t + 1];
    int pinc = a0 + a1;
    ps[t] = pinc;
    __syncthreads();
    for (int off = 1; off < 256; off <<= 1) {
        int y = (t >= off) ? ps[t - off] : 0;
        __syncthreads();
        pinc += y;
        ps[t] = pinc;
        __syncthreads();
    }
    int pexc = pinc - a0 - a1;
    if (2 * t < NB) {
        lstart[2 * t] = pexc;
        lcur[2 * t] = pexc;
        gbase[2 * t] = a0 ? atomicAdd(&gcursor[2 * t], a0) : 0;
    }
    if (2 * t + 1 < NB) {
        lstart[2 * t + 1] = pexc + a0;
        lcur[2 * t + 1] = pexc + a0;
        gbase[2 * t + 1] = a1 ? atomicAdd(&gcursor[2 * t + 1], a1) : 0;
    }
    __syncthreads();

    // local scatter into LDS (sorted by bin)
    #pragma unroll
    for (int i = 0; i < EPT; ++i) {
        if (d[i] >= 0) {
            int b = d[i] >> 8;
            int pos = atomicAdd(&lcur[b], 1);
            sortedv[pos] = ((unsigned)s[i] << 8) | (unsigned)(d[i] & 255);
            binof[pos] = (unsigned short)b;
        }
    }
    __syncthreads();

    // emission: consecutive k -> ascending global addresses (coalesced runs)
    int cnt = min(EPB, N_EDGES - base);
    for (int k = t; k < cnt; k += 256) {
        int b = binof[k];
        packed[gbase[b] + (k - lstart[b])] = sortedv[k];
    }
}

// ---------------- refine (padded): per-bucket CSR padded to mult-of-8 + norm ----------------
__global__ __launch_bounds__(256) void refine_pad_kernel(const unsigned int* __restrict__ packed,
                                                         const int* __restrict__ boffs,
                                                         int* __restrict__ ssp,
                                                         int* __restrict__ pbeg,
                                                         int* __restrict__ pdega,
                                                         float* __restrict__ norm) {
    __shared__ int h[NPB];
    __shared__ int sc[NPB];
    __shared__ int cur[NPB];
    int b = blockIdx.x, t = threadIdx.x;
    int beg = boffs[b], end = boffs[b + 1];
    h[t] = 0;
    __syncthreads();
    for (int j = beg + t; j < end; j += 256)
        atomicAdd(&h[packed[j] & 255], 1);
    __syncthreads();
    int deg = h[t];
    int pdeg = (deg + 7) & ~7;            // deg==0 -> 0 (no pad slots)
    int inc = pdeg;
    sc[t] = inc;
    __syncthreads();
    for (int off = 1; off < 256; off <<= 1) {
        int y = (t >= off) ? sc[t - off] : 0;
        __syncthreads();
        inc += y;
        sc[t] = inc;
        __syncthreads();
    }
    int exc = inc - pdeg;
    int pb = beg + b * CAPPAD + exc;      // absolute padded begin (capacity layout)
    cur[t] = pb;
    int n = b * NPB + t;
    pbeg[n] = pb;
    pdega[n] = pdeg;
    if (n < N_NODES) norm[n] = rsqrtf((float)(deg < 1 ? 1 : deg));
    __syncthreads();
    for (int j = beg + t; j < end; j += 256) {
        unsigned p = packed[j];
        int pos = atomicAdd(&cur[p & 255], 1);
        ssp[pos] = (int)(p >> 8);
    }
    __syncthreads();
    int fend = pb + pdeg;                  // fill pad slots with dummy (<=7)
    for (int k = cur[t]; k < fend; ++k) ssp[k] = DUMMY;
}

// ---------------- refine (fallback, R6-proven): exact CSR + norm ----------------
__global__ __launch_bounds__(256) void refine_kernel(const unsigned int* __restrict__ packed,
                                                     const int* __restrict__ boffs,
                                                     int* __restrict__ ssorted,
                                                     int* __restrict__ offs,
                                                     float* __restrict__ norm) {
    __shared__ int h[NPB];
    __shared__ int sc[NPB];
    __shared__ int cur[NPB];
    int b = blockIdx.x, t = threadIdx.x;
    int beg = boffs[b], end = boffs[b + 1];
    h[t] = 0;
    __syncthreads();
    for (int j = beg + t; j < end; j += 256)
        atomicAdd(&h[packed[j] & 255], 1);
    __syncthreads();
    int v = h[t], inc = v;
    sc[t] = inc;
    __syncthreads();
    for (int off = 1; off < 256; off <<= 1) {
        int y = (t >= off) ? sc[t - off] : 0;
        __syncthreads();
        inc += y;
        sc[t] = inc;
        __syncthreads();
    }
    int exc = inc - v;
    cur[t] = beg + exc;
    int n = b * NPB + t;
    offs[n] = beg + exc;
    if (n < N_NODES) norm[n] = rsqrtf((float)(v < 1 ? 1 : v));
    __syncthreads();
    for (int j = beg + t; j < end; j += 256) {
        unsigned p = packed[j];
        int pos = atomicAdd(&cur[p & 255], 1);
        ssorted[pos] = (int)(p >> 8);
    }
}

// ---------------- prep: featn[n][k] = bf16(feat[n][k]*norm[n]); rows >= N_NODES zeroed ----------------
__global__ __launch_bounds__(256) void prep_kernel(const float* __restrict__ feat,
                                                   const float* __restrict__ norm,
                                                   unsigned short* __restrict__ featn) {
    int g = blockIdx.x * 256 + threadIdx.x;       // < NPAD2*16
    int n = g >> 4;
    uint2 r = make_uint2(0u, 0u);
    if (n < N_NODES) {
        float nn = norm[n];
        float4 f = *(const float4*)&feat[(size_t)g * 4];
        auto cvt = [](float x) -> unsigned {
            unsigned u = __float_as_uint(x);
            return (u + 0x7fff + ((u >> 16) & 1)) >> 16;
        };
        r.x = cvt(f.x * nn) | (cvt(f.y * nn) << 16);
        r.y = cvt(f.z * nn) | (cvt(f.w * nn) << 16);
    }
    *(uint2*)&featn[(size_t)g * 4] = r;
}

#define ACC_EDGE(SSARR, J) do {                                       \
        int s_ = SSARR[(J)];                                          \
        uint2 r_ = *(const uint2*)&featn[(size_t)s_ * D + m * 4];     \
        acc.x += __uint_as_float(r_.x << 16);                         \
        acc.y += __uint_as_float(r_.x & 0xffff0000u);                 \
        acc.z += __uint_as_float(r_.y << 16);                         \
        acc.w += __uint_as_float(r_.y & 0xffff0000u);                 \
    } while (0)

// ---------------- gather (padded): no tail, always 4-deep load pipeline ----------------
__global__ __launch_bounds__(256) void gather_pad_kernel(const unsigned short* __restrict__ featn,
                                                         const int* __restrict__ ssp,
                                                         const int* __restrict__ pbeg,
                                                         const int* __restrict__ pdega,
                                                         const float* __restrict__ norm,
                                                         float* __restrict__ out) {
    int n = blockIdx.x * 4 + (threadIdx.x >> 6);
    int lane = threadIdx.x & 63;
    if (n >= N_NODES) return;
    int beg = pbeg[n], end = beg + pdega[n];
    int q = lane >> 4, m = lane & 15;
    float4 acc = make_float4(0.f, 0.f, 0.f, 0.f);
    int j = beg;
    for (; j + 16 <= end; j += 16) {
        ACC_EDGE(ssp, j + q);
        ACC_EDGE(ssp, j + 4 + q);
        ACC_EDGE(ssp, j + 8 + q);
        ACC_EDGE(ssp, j + 12 + q);
    }
    if (j < end) {                 // exactly 8 remain
        ACC_EDGE(ssp, j + q);
        ACC_EDGE(ssp, j + 4 + q);
    }
    #pragma unroll
    for (int mask = 16; mask <= 32; mask <<= 1) {
        acc.x += __shfl_xor(acc.x, mask);
        acc.y += __shfl_xor(acc.y, mask);
        acc.z += __shfl_xor(acc.z, mask);
        acc.w += __shfl_xor(acc.w, mask);
    }
    if (q == 0) {
        float nn = norm[n];
        *(float4*)&out[(size_t)n * D + m * 4] =
            make_float4(acc.x * nn, acc.y * nn, acc.z * nn, acc.w * nn);
    }
}

// ---------------- gather (fallback, R6-proven) ----------------
__global__ __launch_bounds__(256) void gather_bf16_kernel(const unsigned short* __restrict__ featn,
                                                          const int* __restrict__ ssorted,
                                                          const int* __restrict__ offs,
                                                          const float* __restrict__ norm,
                                                          float* __restrict__ out) {
    int n = blockIdx.x * 4 + (threadIdx.x >> 6);
    int lane = threadIdx.x & 63;
    if (n >= N_NODES) return;
    int beg = offs[n], end = offs[n + 1];
    int q = lane >> 4, m = lane & 15;
    float4 acc = make_float4(0.f, 0.f, 0.f, 0.f);
    int j = beg;
    for (; j + 16 <= end; j += 16) {
        ACC_EDGE(ssorted, j + q);
        ACC_EDGE(ssorted, j + 4 + q);
        ACC_EDGE(ssorted, j + 8 + q);
        ACC_EDGE(ssorted, j + 12 + q);
    }
    for (; j + 4 <= end; j += 4) ACC_EDGE(ssorted, j + q);
    if (j + q < end) ACC_EDGE(ssorted, j + q);
    #pragma unroll
    for (int mask = 16; mask <= 32; mask <<= 1) {
        acc.x += __shfl_xor(acc.x, mask);
        acc.y += __shfl_xor(acc.y, mask);
        acc.z += __shfl_xor(acc.z, mask);
        acc.w += __shfl_xor(acc.w, mask);
    }
    if (q == 0) {
        float nn = norm[n];
        *(float4*)&out[(size_t)n * D + m * 4] =
            make_float4(acc.x * nn, acc.y * nn, acc.z * nn, acc.w * nn);
    }
}

// ---------------- GEMM: out = h @ W^T + bias, in-place on d_out ----------------
#define GPAD 68
__global__ __launch_bounds__(256) void gemm64_kernel(const float* __restrict__ weight,
                                                     const float* __restrict__ bias,
                                                     float* __restrict__ io) {
    __shared__ float Ht[D * GPAD];   // Ht[k][n]
    __shared__ float Wt[D * GPAD];   // Wt[k][d]
    int tid = threadIdx.x;
    int n0 = blockIdx.x * 64;
    int c = tid & 63;
    int r4 = tid >> 6;

    for (int dd = r4; dd < D; dd += 4)
        Wt[c * GPAD + dd] = weight[dd * D + c];
    for (int nl = r4; nl < 64; nl += 4) {
        int n = n0 + nl;
        Ht[c * GPAD + nl] = (n < N_NODES) ? io[(size_t)n * D + c] : 0.f;
    }
    __syncthreads();

    int tx = tid & 15, ty = tid >> 4;
    float acc[4][4] = {};
    #pragma unroll 8
    for (int k = 0; k < D; ++k) {
        float4 a = *(const float4*)&Ht[k * GPAD + ty * 4];
        float4 b = *(const float4*)&Wt[k * GPAD + tx * 4];
        acc[0][0] += a.x * b.x; acc[0][1] += a.x * b.y; acc[0][2] += a.x * b.z; acc[0][3] += a.x * b.w;
        acc[1][0] += a.y * b.x; acc[1][1] += a.y * b.y; acc[1][2] += a.y * b.z; acc[1][3] += a.y * b.w;
        acc[2][0] += a.z * b.x; acc[2][1] += a.z * b.y; acc[2][2] += a.z * b.z; acc[2][3] += a.z * b.w;
        acc[3][0] += a.w * b.x; acc[3][1] += a.w * b.y; acc[3][2] += a.w * b.z; acc[3][3] += a.w * b.w;
    }

    float4 bv = *(const float4*)&bias[tx * 4];
    #pragma unroll
    for (int i = 0; i < 4; ++i) {
        int n = n0 + ty * 4 + i;
        if (n < N_NODES) {
            *(float4*)&io[(size_t)n * D + tx * 4] =
                make_float4(acc[i][0] + bv.x, acc[i][1] + bv.y,
                            acc[i][2] + bv.z, acc[i][3] + bv.w);
        }
    }
}

extern "C" void kernel_launch(void* const* d_in, const int* in_sizes, int n_in,
                              void* d_out, int out_size, void* d_ws, size_t ws_size,
                              hipStream_t stream) {
    const float* feat   = (const float*)d_in[0];
    const int*   src    = (const int*)d_in[1];
    const int*   dst    = (const int*)d_in[2];
    const float* weight = (const float*)d_in[3];
    const float* bias   = (const float*)d_in[4];
    float* out = (float*)d_out;

    const size_t META   = (size_t)(3 * NB + 1);                 // ints
    const size_t FEATN_BYTES = (size_t)NPAD2 * D * 2;           // 12,812,288
    // padded layout: meta | pbeg | pdega | norm | ssp | featn(>=packed overlay)
    const size_t REQ_PAD  = (META + 3 * (size_t)NPAD2 + SSP_CAP) * 4 + FEATN_BYTES; // ~21.8 MB
    // fallback layout: meta | offs | norm | ssorted | featn(>=packed overlay)
    const size_t REQ_FB   = (META + 2 * (size_t)NPAD2 + N_EDGES) * 4 + FEATN_BYTES; // ~18.6 MB

    int* w = (int*)d_ws;
    int* bhist   = w;
    int* boffs   = bhist + NB;
    int* gcursor = boffs + NB + 1;

    hipMemsetAsync(bhist, 0, NB * sizeof(int), stream);
    hist_kernel       <<<NBLK, 256, 0, stream>>>(dst, bhist);
    bucket_scan_kernel<<<1, 512, 0, stream>>>(bhist, boffs, gcursor);

    if (ws_size >= REQ_PAD) {
        int*      pbeg   = gcursor + NB;                       // [NPAD2]
        int*      pdega  = pbeg + NPAD2;                       // [NPAD2]
        float*    norm   = (float*)(pdega + NPAD2);            // [NPAD2]
        int*      ssp    = (int*)(norm + NPAD2);               // [SSP_CAP]
        unsigned* packed = (unsigned*)(ssp + SSP_CAP);         // [N_EDGES], overlaid by featn
        unsigned short* featn = (unsigned short*)packed;       // [NPAD2*D]

        place_kernel     <<<NBLK, 256, 0, stream>>>(src, dst, gcursor, packed);
        refine_pad_kernel<<<NB, 256, 0, stream>>>(packed, boffs, ssp, pbeg, pdega, norm);
        prep_kernel      <<<NPAD2 * 16 / 256, 256, 0, stream>>>(feat, norm, featn);
        gather_pad_kernel<<<(N_NODES + 3) / 4, 256, 0, stream>>>(featn, ssp, pbeg, pdega, norm, out);
    } else {
        int*      offs    = gcursor + NB;                      // [NPAD2]
        float*    norm    = (float*)(offs + NPAD2);            // [NPAD2]
        int*      ssorted = (int*)(norm + NPAD2);              // [N_EDGES]
        unsigned* packed  = (unsigned*)(ssorted + N_EDGES);    // [N_EDGES], overlaid by featn
        unsigned short* featn = (unsigned short*)packed;       // [NPAD2*D]
        (void)REQ_FB;

        place_kernel      <<<NBLK, 256, 0, stream>>>(src, dst, gcursor, packed);
        refine_kernel     <<<NB, 256, 0, stream>>>(packed, boffs, ssorted, offs, norm);
        prep_kernel       <<<NPAD2 * 16 / 256, 256, 0, stream>>>(feat, norm, featn);
        gather_bf16_kernel<<<(N_NODES + 3) / 4, 256, 0, stream>>>(featn, ssorted, offs, norm, out);
    }
    gemm64_kernel<<<(N_NODES + 63) / 64, 256, 0, stream>>>(weight, bias, out);
}